// Round 20
// baseline (70.883 us; speedup 1.0000x reference)
//
#include <hip/hip_runtime.h>
#include <hip/hip_bf16.h>

// Problem constants
#define NA 32      // agents per graph
#define NACT 64    // actions
#define NIN 128    // in_dim
#define NOUT 128   // out_dim
#define NB 256     // graphs
// Inputs f32. Outputs f32: obs_final [8192,32,192] then w_out [8192,32,1].
//
// Round 20: decompose the copy stream away from the 49.5 KB-LDS kernel.
//   K1: qk (256 blocks) + 2048 copy rows  — LDS-heavy, short.
//   KB: 6144 copy rows, ZERO LDS -> 8 blocks/CU, pure NT write stream.
//   KC: z_mix (R19 verbatim).

typedef float floatx4 __attribute__((ext_vector_type(4)));

__device__ __forceinline__ void nt_store4(float4* p, float4 v) {
    floatx4 nv = {v.x, v.y, v.z, v.w};
    __builtin_nontemporal_store(nv, reinterpret_cast<floatx4*>(p));
}
__device__ __forceinline__ float4 nt_load4(const float4* p) {
    floatx4 nv = __builtin_nontemporal_load(
        reinterpret_cast<const floatx4*>(p));
    return make_float4(nv.x, nv.y, nv.z, nv.w);
}

// ---------------------------------------------------------------------------
// K1: 2304 blocks x 256.  bid<256: qk -> w_out.  bid>=256: copy rows 0..2047
// (XCD-swizzled: xcd handles graphs 8*xcd..8*xcd+7).
// ---------------------------------------------------------------------------
__global__ __launch_bounds__(256) void k1_qk_obscopy(
    const float* __restrict__ h,
    const float* __restrict__ Wk, const float* __restrict__ bk,
    const float* __restrict__ Wq, const float* __restrict__ bq,
    const float* __restrict__ obs,
    float* __restrict__ out, float* __restrict__ w_out)
{
    __shared__ float sh[NA][NIN];         // 16 KB
    __shared__ float sK[NA][NOUT + 4];    // 16.5 KB
    __shared__ float sQ[NA][NOUT + 4];    // 16.5 KB

    const int bid = blockIdx.x;
    const int tid = threadIdx.x;

    if (bid >= NB) {
        const int x   = bid - NB;                 // 0..2047
        const int xcd = x & 7;
        const int idx = x >> 3;                   // 0..255
        const int gr  = xcd * 256 + idx;          // rows 0..2047
        const int b   = gr >> 5;
        const float4* so4 = reinterpret_cast<const float4*>(obs + (size_t)b * NA * NIN);
        float4* out4 = reinterpret_cast<float4*>(out) + (size_t)gr * 1536;
#pragma unroll
        for (int kk = 0; kk < 4; ++kk) {
            const int m = tid + 256 * kk;         // 0..1023
            nt_store4(&out4[(m >> 5) * 48 + (m & 31)], so4[m]);
        }
        return;
    }

    const int g = bid;

    {
        const float4* hs = reinterpret_cast<const float4*>(h + (size_t)g * NA * NIN);
        float4* shl = reinterpret_cast<float4*>(&sh[0][0]);
#pragma unroll
        for (int kk = 0; kk < 4; ++kk) { const int m = tid + 256 * kk; shl[m] = hs[m]; }
    }
    __syncthreads();

    // projection: txg = tid&31 (4 out-dims), ty = tid>>5 (4 nodes)
    {
        const int txg = tid & 31;
        const int ty  = tid >> 5;
        float4 kacc[4], qacc[4];
        const float4 bk4 = *reinterpret_cast<const float4*>(bk + txg * 4);
        const float4 bq4 = *reinterpret_cast<const float4*>(bq + txg * 4);
#pragma unroll
        for (int s = 0; s < 4; ++s) { kacc[s] = bk4; qacc[s] = bq4; }

        for (int rr4 = 0; rr4 < NIN; rr4 += 4) {
            float4 wk[4], wq[4];
#pragma unroll
            for (int rr = 0; rr < 4; ++rr) {
                wk[rr] = *reinterpret_cast<const float4*>(Wk + (size_t)(rr4 + rr) * NOUT + txg * 4);
                wq[rr] = *reinterpret_cast<const float4*>(Wq + (size_t)(rr4 + rr) * NOUT + txg * 4);
            }
#pragma unroll
            for (int s = 0; s < 4; ++s) {
                const float4 hv = *reinterpret_cast<const float4*>(&sh[ty * 4 + s][rr4]);
                kacc[s].x = fmaf(hv.x, wk[0].x, fmaf(hv.y, wk[1].x, fmaf(hv.z, wk[2].x, fmaf(hv.w, wk[3].x, kacc[s].x))));
                kacc[s].y = fmaf(hv.x, wk[0].y, fmaf(hv.y, wk[1].y, fmaf(hv.z, wk[2].y, fmaf(hv.w, wk[3].y, kacc[s].y))));
                kacc[s].z = fmaf(hv.x, wk[0].z, fmaf(hv.y, wk[1].z, fmaf(hv.z, wk[2].z, fmaf(hv.w, wk[3].z, kacc[s].z))));
                kacc[s].w = fmaf(hv.x, wk[0].w, fmaf(hv.y, wk[1].w, fmaf(hv.z, wk[2].w, fmaf(hv.w, wk[3].w, kacc[s].w))));
                qacc[s].x = fmaf(hv.x, wq[0].x, fmaf(hv.y, wq[1].x, fmaf(hv.z, wq[2].x, fmaf(hv.w, wq[3].x, qacc[s].x))));
                qacc[s].y = fmaf(hv.x, wq[0].y, fmaf(hv.y, wq[1].y, fmaf(hv.z, wq[2].y, fmaf(hv.w, wq[3].y, qacc[s].y))));
                qacc[s].z = fmaf(hv.x, wq[0].z, fmaf(hv.y, wq[1].z, fmaf(hv.z, wq[2].z, fmaf(hv.w, wq[3].z, qacc[s].z))));
                qacc[s].w = fmaf(hv.x, wq[0].w, fmaf(hv.y, wq[1].w, fmaf(hv.z, wq[2].w, fmaf(hv.w, wq[3].w, qacc[s].w))));
            }
        }
#pragma unroll
        for (int s = 0; s < 4; ++s) {
            *reinterpret_cast<float4*>(&sK[ty * 4 + s][txg * 4]) = kacc[s];
            *reinterpret_cast<float4*>(&sQ[ty * 4 + s][txg * 4]) = qacc[s];
        }
    }
    __syncthreads();

    // scores + softmax: i = tid>>3 (dst row), jg = tid&7 (4 src j's)
    {
        const int i  = tid >> 3;
        const int jg = tid & 7;
        float sc[4] = {0.f, 0.f, 0.f, 0.f};
        for (int rr4 = 0; rr4 < NOUT; rr4 += 4) {
            const float4 qv = *reinterpret_cast<const float4*>(&sQ[i][rr4]);
#pragma unroll
            for (int jj = 0; jj < 4; ++jj) {
                const float4 kv = *reinterpret_cast<const float4*>(&sK[jg * 4 + jj][rr4]);
                sc[jj] = fmaf(qv.x, kv.x, fmaf(qv.y, kv.y, fmaf(qv.z, kv.z, fmaf(qv.w, kv.w, sc[jj]))));
            }
        }
#pragma unroll
        for (int jj = 0; jj < 4; ++jj) sc[jj] *= 0.08838834764831845f;  // 1/sqrt(128)

        float m = fmaxf(fmaxf(sc[0], sc[1]), fmaxf(sc[2], sc[3]));
        m = fmaxf(m, __shfl_xor(m, 1));
        m = fmaxf(m, __shfl_xor(m, 2));
        m = fmaxf(m, __shfl_xor(m, 4));
        float e[4];
#pragma unroll
        for (int jj = 0; jj < 4; ++jj) e[jj] = __expf(sc[jj] - m);
        float ssum = e[0] + e[1] + e[2] + e[3];
        ssum += __shfl_xor(ssum, 1);
        ssum += __shfl_xor(ssum, 2);
        ssum += __shfl_xor(ssum, 4);
        const float inv = 1.0f / ssum;

        *reinterpret_cast<float4*>(w_out + ((size_t)g * NA + i) * NA + jg * 4) =
            make_float4(e[0] * inv, e[1] * inv, e[2] * inv, e[3] * inv);
    }
}

// ---------------------------------------------------------------------------
// KB: copy-only, ZERO LDS. 6144 blocks x 256; rows 2048..8191, XCD-swizzled
// (xcd handles 768 consecutive rows = 24 graphs).
// ---------------------------------------------------------------------------
__global__ __launch_bounds__(256) void kb_obscopy(
    const float* __restrict__ obs, float* __restrict__ out)
{
    const int x   = blockIdx.x;               // 0..6143
    const int tid = threadIdx.x;
    const int xcd = x & 7;
    const int idx = x >> 3;                   // 0..767
    const int gr  = 2048 + xcd * 768 + idx;   // rows 2048..8191
    const int b   = gr >> 5;
    const float4* so4 = reinterpret_cast<const float4*>(obs + (size_t)b * NA * NIN);
    float4* out4 = reinterpret_cast<float4*>(out) + (size_t)gr * 1536;
#pragma unroll
    for (int kk = 0; kk < 4; ++kk) {
        const int m = tid + 256 * kk;         // 0..1023
        nt_store4(&out4[(m >> 5) * 48 + (m & 31)], so4[m]);
    }
}

// ---------------------------------------------------------------------------
// KC: z_mix (R19 verbatim). grid=1024, block=256 (4 waves), XCD-swizzled;
// wave owns 2 rows, both rows' noise loads up front. u = w*d + n,
// z_mix = (P + U - u)/32.
// ---------------------------------------------------------------------------
__global__ __launch_bounds__(256) void k2_zmix(
    const float* __restrict__ policies, const float* __restrict__ actions,
    const float* __restrict__ noise, const float* __restrict__ w_in,
    float* __restrict__ out)
{
    __shared__ float sd[2048];        // 8 KB  act - pi
    __shared__ float sww[256];        // 1 KB
    __shared__ float spart[4][64];    // 1 KB
    __shared__ float szP[64];         // 256 B

    const int blk  = blockIdx.x;  // 0..1023
    const int xcd  = blk & 7;
    const int rest = blk >> 3;
    const int kk2  = rest >> 2;
    const int s    = rest & 3;
    const int b    = xcd + 8 * kk2;   // graph
    const int row0 = b * NA + s * 8;  // first of this block's 8 dst rows
    const int tid  = threadIdx.x;
    const int wv   = tid >> 6;
    const int lane = tid & 63;

    {
        const float4* ps = reinterpret_cast<const float4*>(policies + (size_t)b * 2048) + 2 * tid;
        const float4* as = reinterpret_cast<const float4*>(actions  + (size_t)b * 2048) + 2 * tid;
        const float4 pA = ps[0], pB = ps[1];
        const float4 aA = as[0], aB = as[1];
        float4* dd = reinterpret_cast<float4*>(sd) + 2 * tid;
        dd[0] = make_float4(aA.x - pA.x, aA.y - pA.y, aA.z - pA.z, aA.w - pA.w);
        dd[1] = make_float4(aB.x - pB.x, aB.y - pB.y, aB.z - pB.z, aB.w - pB.w);
        sww[tid] = w_in[(size_t)row0 * NA + tid];

        float p8[8] = {pA.x, pA.y, pA.z, pA.w, pB.x, pB.y, pB.z, pB.w};
#pragma unroll
        for (int k = 0; k < 8; ++k) {
            float v = p8[k];
            v += __shfl_xor(v, 8);
            v += __shfl_xor(v, 16);
            v += __shfl_xor(v, 32);
            if (lane < 8) spart[wv][lane * 8 + k] = v;
        }
    }
    __syncthreads();
    if (tid < 64) {
        szP[tid] = spart[0][tid] + spart[1][tid] + spart[2][tid] + spart[3][tid];
    }
    __syncthreads();

    const int qq   = lane >> 4;
    const int cg   = lane & 15;
    const int c0   = cg * 4;
    const int lr0  = wv * 2;
    const size_t r0 = (size_t)row0 + lr0;

    const float4 P4 = *reinterpret_cast<const float4*>(&szP[c0]);

    const float* nz0 = noise + r0 * 2048 + qq * 512 + c0;
    const float* nz1 = nz0 + 2048;
    float4 A[8], B[8];
#pragma unroll
    for (int tt = 0; tt < 8; ++tt) A[tt] = nt_load4(reinterpret_cast<const float4*>(nz0 + tt * 64));
#pragma unroll
    for (int tt = 0; tt < 8; ++tt) B[tt] = nt_load4(reinterpret_cast<const float4*>(nz1 + tt * 64));

    auto do_row = [&](const float4* BUF, int lr, size_t gr) {
        const float* wr = &sww[lr * 32];
        float4 u[8];
        float S0 = 0.f, S1 = 0.f, S2 = 0.f, S3 = 0.f;
#pragma unroll
        for (int tt = 0; tt < 8; ++tt) {
            const int t = qq * 8 + tt;
            const float wt = wr[t];
            const float4 d4 = *reinterpret_cast<const float4*>(&sd[t * 64 + c0]);
            const float4 n4 = BUF[tt];
            float4 uv;
            uv.x = fmaf(wt, d4.x, n4.x); S0 += uv.x;
            uv.y = fmaf(wt, d4.y, n4.y); S1 += uv.y;
            uv.z = fmaf(wt, d4.z, n4.z); S2 += uv.z;
            uv.w = fmaf(wt, d4.w, n4.w); S3 += uv.w;
            u[tt] = uv;
        }
        S0 += __shfl_xor(S0, 16); S0 += __shfl_xor(S0, 32);
        S1 += __shfl_xor(S1, 16); S1 += __shfl_xor(S1, 32);
        S2 += __shfl_xor(S2, 16); S2 += __shfl_xor(S2, 32);
        S3 += __shfl_xor(S3, 16); S3 += __shfl_xor(S3, 32);

        const float4 T4 = make_float4((P4.x + S0) * (1.0f / NA),
                                      (P4.y + S1) * (1.0f / NA),
                                      (P4.z + S2) * (1.0f / NA),
                                      (P4.w + S3) * (1.0f / NA));
        float4* out4 = reinterpret_cast<float4*>(out) + gr * 1536;
#pragma unroll
        for (int tt = 0; tt < 8; ++tt) {
            const int t = qq * 8 + tt;
            float4 o;
            o.x = fmaf(u[tt].x, -(1.0f / NA), T4.x);
            o.y = fmaf(u[tt].y, -(1.0f / NA), T4.y);
            o.z = fmaf(u[tt].z, -(1.0f / NA), T4.z);
            o.w = fmaf(u[tt].w, -(1.0f / NA), T4.w);
            nt_store4(&out4[t * 48 + 32 + cg], o);
        }
    };

    do_row(A, lr0, r0);
    do_row(B, lr0 + 1, r0 + 1);
}

extern "C" void kernel_launch(void* const* d_in, const int* in_sizes, int n_in,
                              void* d_out, int out_size, void* d_ws, size_t ws_size,
                              hipStream_t stream) {
    const float* h        = (const float*)d_in[0];
    const float* policies = (const float*)d_in[1];
    const float* actions  = (const float*)d_in[2];
    const float* obs_proc = (const float*)d_in[3];
    const float* noise    = (const float*)d_in[4];
    const float* Wk       = (const float*)d_in[5];
    const float* bk       = (const float*)d_in[6];
    const float* Wq       = (const float*)d_in[7];
    const float* bq       = (const float*)d_in[8];

    float* out = (float*)d_out;
    float* obs_final = out;                                      // [8192,32,192]
    float* w_out = out + (size_t)NB * NA * NA * (NIN + NACT);    // [8192,32,1]

    k1_qk_obscopy<<<NB + 2048, 256, 0, stream>>>(h, Wk, bk, Wq, bq, obs_proc,
                                                 obs_final, w_out);
    kb_obscopy<<<6144, 256, 0, stream>>>(obs_proc, obs_final);
    k2_zmix<<<1024, 256, 0, stream>>>(policies, actions, noise, w_out, obs_final);
}

// Round 21
// 58.805 us; speedup vs baseline: 1.2054x; 1.2054x over previous
//
#include <hip/hip_runtime.h>
#include <hip/hip_bf16.h>

// Problem constants
#define NA 32      // agents per graph
#define NACT 64    // actions
#define NIN 128    // in_dim
#define NOUT 128   // out_dim
#define NB 256     // graphs
// Inputs f32. Outputs f32: obs_final [8192,32,192] then w_out [8192,32,1].
//
// Round 21 = R18 two-dispatch structure (best, 59.2) with K2 rebuilt as
// long-lived rolling waves: 512 blocks x 4 waves, wave owns 4 rows with a
// rolling A/B noise pipeline -> loads of row k+2 overlap stores of row k,
// waves desync, HBM sees a continuous mixed stream.

typedef float floatx4 __attribute__((ext_vector_type(4)));

__device__ __forceinline__ void nt_store4(float4* p, float4 v) {
    floatx4 nv = {v.x, v.y, v.z, v.w};
    __builtin_nontemporal_store(nv, reinterpret_cast<floatx4*>(p));
}
__device__ __forceinline__ float4 nt_load4(const float4* p) {
    floatx4 nv = __builtin_nontemporal_load(
        reinterpret_cast<const floatx4*>(p));
    return make_float4(nv.x, nv.y, nv.z, nv.w);
}

// ---------------------------------------------------------------------------
// K1: 8448 blocks x 256.  bid<256: qk -> w_out.  bid>=256: obs-copy row,
// XCD-swizzled so each graph's 32 rows are on one XCD. (R18 verbatim)
// ---------------------------------------------------------------------------
__global__ __launch_bounds__(256) void k1_qk_obscopy(
    const float* __restrict__ h,
    const float* __restrict__ Wk, const float* __restrict__ bk,
    const float* __restrict__ Wq, const float* __restrict__ bq,
    const float* __restrict__ obs,
    float* __restrict__ out, float* __restrict__ w_out)
{
    __shared__ float sh[NA][NIN];         // 16 KB
    __shared__ float sK[NA][NOUT + 4];    // 16.5 KB
    __shared__ float sQ[NA][NOUT + 4];    // 16.5 KB

    const int bid = blockIdx.x;
    const int tid = threadIdx.x;

    if (bid >= NB) {
        const int x   = bid - NB;
        const int xcd = x & 7;
        const int idx = x >> 3;                       // 0..1023
        const int gr  = xcd * 32 + (idx >> 5) * 256 + (idx & 31);
        const int b   = gr >> 5;
        const float4* so4 = reinterpret_cast<const float4*>(obs + (size_t)b * NA * NIN);
        float4* out4 = reinterpret_cast<float4*>(out) + (size_t)gr * 1536;
#pragma unroll
        for (int kk = 0; kk < 4; ++kk) {
            const int m = tid + 256 * kk;             // 0..1023
            nt_store4(&out4[(m >> 5) * 48 + (m & 31)], so4[m]);
        }
        return;
    }

    const int g = bid;

    {
        const float4* hs = reinterpret_cast<const float4*>(h + (size_t)g * NA * NIN);
        float4* shl = reinterpret_cast<float4*>(&sh[0][0]);
#pragma unroll
        for (int kk = 0; kk < 4; ++kk) { const int m = tid + 256 * kk; shl[m] = hs[m]; }
    }
    __syncthreads();

    // projection: txg = tid&31 (4 out-dims), ty = tid>>5 (4 nodes)
    {
        const int txg = tid & 31;
        const int ty  = tid >> 5;
        float4 kacc[4], qacc[4];
        const float4 bk4 = *reinterpret_cast<const float4*>(bk + txg * 4);
        const float4 bq4 = *reinterpret_cast<const float4*>(bq + txg * 4);
#pragma unroll
        for (int s = 0; s < 4; ++s) { kacc[s] = bk4; qacc[s] = bq4; }

        for (int rr4 = 0; rr4 < NIN; rr4 += 4) {
            float4 wk[4], wq[4];
#pragma unroll
            for (int rr = 0; rr < 4; ++rr) {
                wk[rr] = *reinterpret_cast<const float4*>(Wk + (size_t)(rr4 + rr) * NOUT + txg * 4);
                wq[rr] = *reinterpret_cast<const float4*>(Wq + (size_t)(rr4 + rr) * NOUT + txg * 4);
            }
#pragma unroll
            for (int s = 0; s < 4; ++s) {
                const float4 hv = *reinterpret_cast<const float4*>(&sh[ty * 4 + s][rr4]);
                kacc[s].x = fmaf(hv.x, wk[0].x, fmaf(hv.y, wk[1].x, fmaf(hv.z, wk[2].x, fmaf(hv.w, wk[3].x, kacc[s].x))));
                kacc[s].y = fmaf(hv.x, wk[0].y, fmaf(hv.y, wk[1].y, fmaf(hv.z, wk[2].y, fmaf(hv.w, wk[3].y, kacc[s].y))));
                kacc[s].z = fmaf(hv.x, wk[0].z, fmaf(hv.y, wk[1].z, fmaf(hv.z, wk[2].z, fmaf(hv.w, wk[3].z, kacc[s].z))));
                kacc[s].w = fmaf(hv.x, wk[0].w, fmaf(hv.y, wk[1].w, fmaf(hv.z, wk[2].w, fmaf(hv.w, wk[3].w, kacc[s].w))));
                qacc[s].x = fmaf(hv.x, wq[0].x, fmaf(hv.y, wq[1].x, fmaf(hv.z, wq[2].x, fmaf(hv.w, wq[3].x, qacc[s].x))));
                qacc[s].y = fmaf(hv.x, wq[0].y, fmaf(hv.y, wq[1].y, fmaf(hv.z, wq[2].y, fmaf(hv.w, wq[3].y, qacc[s].y))));
                qacc[s].z = fmaf(hv.x, wq[0].z, fmaf(hv.y, wq[1].z, fmaf(hv.z, wq[2].z, fmaf(hv.w, wq[3].z, qacc[s].z))));
                qacc[s].w = fmaf(hv.x, wq[0].w, fmaf(hv.y, wq[1].w, fmaf(hv.z, wq[2].w, fmaf(hv.w, wq[3].w, qacc[s].w))));
            }
        }
#pragma unroll
        for (int s = 0; s < 4; ++s) {
            *reinterpret_cast<float4*>(&sK[ty * 4 + s][txg * 4]) = kacc[s];
            *reinterpret_cast<float4*>(&sQ[ty * 4 + s][txg * 4]) = qacc[s];
        }
    }
    __syncthreads();

    // scores + softmax: i = tid>>3 (dst row), jg = tid&7 (4 src j's)
    {
        const int i  = tid >> 3;
        const int jg = tid & 7;
        float sc[4] = {0.f, 0.f, 0.f, 0.f};
        for (int rr4 = 0; rr4 < NOUT; rr4 += 4) {
            const float4 qv = *reinterpret_cast<const float4*>(&sQ[i][rr4]);
#pragma unroll
            for (int jj = 0; jj < 4; ++jj) {
                const float4 kv = *reinterpret_cast<const float4*>(&sK[jg * 4 + jj][rr4]);
                sc[jj] = fmaf(qv.x, kv.x, fmaf(qv.y, kv.y, fmaf(qv.z, kv.z, fmaf(qv.w, kv.w, sc[jj]))));
            }
        }
#pragma unroll
        for (int jj = 0; jj < 4; ++jj) sc[jj] *= 0.08838834764831845f;  // 1/sqrt(128)

        float m = fmaxf(fmaxf(sc[0], sc[1]), fmaxf(sc[2], sc[3]));
        m = fmaxf(m, __shfl_xor(m, 1));
        m = fmaxf(m, __shfl_xor(m, 2));
        m = fmaxf(m, __shfl_xor(m, 4));
        float e[4];
#pragma unroll
        for (int jj = 0; jj < 4; ++jj) e[jj] = __expf(sc[jj] - m);
        float ssum = e[0] + e[1] + e[2] + e[3];
        ssum += __shfl_xor(ssum, 1);
        ssum += __shfl_xor(ssum, 2);
        ssum += __shfl_xor(ssum, 4);
        const float inv = 1.0f / ssum;

        *reinterpret_cast<float4*>(w_out + ((size_t)g * NA + i) * NA + jg * 4) =
            make_float4(e[0] * inv, e[1] * inv, e[2] * inv, e[3] * inv);
    }
}

// ---------------------------------------------------------------------------
// K2 v3: rolling-wave z_mix. grid=512, block=256 (4 waves). Block ->
// (graph b, half): 16 rows; wave owns 4 rows, rolling A/B noise pipeline.
//   u = w*d + n (d = act-pi in LDS), z_mix = (P + U - u)/32.
// ---------------------------------------------------------------------------
__global__ __launch_bounds__(256) void k2_zmix(
    const float* __restrict__ policies, const float* __restrict__ actions,
    const float* __restrict__ noise, const float* __restrict__ w_in,
    float* __restrict__ out)
{
    __shared__ float sd[2048];        // 8 KB  act - pi
    __shared__ float sww[512];        // 2 KB  16 rows x 32 w
    __shared__ float spart[4][64];    // 1 KB  per-wave pi column partials
    __shared__ float szP[64];         // 256 B P[c]

    const int blk  = blockIdx.x;      // 0..511
    const int xcd  = blk & 7;
    const int rest = blk >> 3;        // 0..63
    const int b    = xcd + 8 * (rest >> 1);   // graph (XCD-affine)
    const int half = rest & 1;
    const int row0 = b * NA + half * 16;      // first of this block's 16 rows
    const int tid  = threadIdx.x;
    const int wv   = tid >> 6;
    const int lane = tid & 63;

    // ---- staging: d = act - pi to LDS; pi column-sum via butterfly
    {
        const float4* ps = reinterpret_cast<const float4*>(policies + (size_t)b * 2048) + 2 * tid;
        const float4* as = reinterpret_cast<const float4*>(actions  + (size_t)b * 2048) + 2 * tid;
        const float4 pA = ps[0], pB = ps[1];
        const float4 aA = as[0], aB = as[1];
        float4* dd = reinterpret_cast<float4*>(sd) + 2 * tid;
        dd[0] = make_float4(aA.x - pA.x, aA.y - pA.y, aA.z - pA.z, aA.w - pA.w);
        dd[1] = make_float4(aB.x - pB.x, aB.y - pB.y, aB.z - pB.z, aB.w - pB.w);
        sww[tid]       = w_in[(size_t)row0 * NA + tid];
        sww[tid + 256] = w_in[(size_t)row0 * NA + tid + 256];

        float p8[8] = {pA.x, pA.y, pA.z, pA.w, pB.x, pB.y, pB.z, pB.w};
#pragma unroll
        for (int k = 0; k < 8; ++k) {
            float v = p8[k];
            v += __shfl_xor(v, 8);
            v += __shfl_xor(v, 16);
            v += __shfl_xor(v, 32);
            if (lane < 8) spart[wv][lane * 8 + k] = v;
        }
    }
    __syncthreads();
    if (tid < 64) {
        szP[tid] = spart[0][tid] + spart[1][tid] + spart[2][tid] + spart[3][tid];
    }
    __syncthreads();

    const int qq   = lane >> 4;   // t-octet 0..3
    const int cg   = lane & 15;   // col group (4 floats)
    const int c0   = cg * 4;
    const int lw0  = wv * 4;                    // local rows lw0..lw0+3
    const size_t r0 = (size_t)row0 + lw0;       // global first row

    const float4 P4 = *reinterpret_cast<const float4*>(&szP[c0]);
    const float* nzb = noise + r0 * 2048 + qq * 512 + c0;

    auto load_row = [&](float4* BUF, int j) {
#pragma unroll
        for (int tt = 0; tt < 8; ++tt)
            BUF[tt] = nt_load4(reinterpret_cast<const float4*>(nzb + (size_t)j * 2048 + tt * 64));
    };

    auto do_row = [&](const float4* BUF, int j) {
        const float* wr = &sww[(lw0 + j) * 32];
        float4 u[8];
        float S0 = 0.f, S1 = 0.f, S2 = 0.f, S3 = 0.f;
#pragma unroll
        for (int tt = 0; tt < 8; ++tt) {
            const int t = qq * 8 + tt;
            const float wt = wr[t];
            const float4 d4 = *reinterpret_cast<const float4*>(&sd[t * 64 + c0]);
            const float4 n4 = BUF[tt];
            float4 uv;
            uv.x = fmaf(wt, d4.x, n4.x); S0 += uv.x;
            uv.y = fmaf(wt, d4.y, n4.y); S1 += uv.y;
            uv.z = fmaf(wt, d4.z, n4.z); S2 += uv.z;
            uv.w = fmaf(wt, d4.w, n4.w); S3 += uv.w;
            u[tt] = uv;
        }
        S0 += __shfl_xor(S0, 16); S0 += __shfl_xor(S0, 32);
        S1 += __shfl_xor(S1, 16); S1 += __shfl_xor(S1, 32);
        S2 += __shfl_xor(S2, 16); S2 += __shfl_xor(S2, 32);
        S3 += __shfl_xor(S3, 16); S3 += __shfl_xor(S3, 32);

        const float4 T4 = make_float4((P4.x + S0) * (1.0f / NA),
                                      (P4.y + S1) * (1.0f / NA),
                                      (P4.z + S2) * (1.0f / NA),
                                      (P4.w + S3) * (1.0f / NA));
        float4* out4 = reinterpret_cast<float4*>(out) + (r0 + j) * 1536;
#pragma unroll
        for (int tt = 0; tt < 8; ++tt) {
            const int t = qq * 8 + tt;
            float4 o;
            o.x = fmaf(u[tt].x, -(1.0f / NA), T4.x);
            o.y = fmaf(u[tt].y, -(1.0f / NA), T4.y);
            o.z = fmaf(u[tt].z, -(1.0f / NA), T4.z);
            o.w = fmaf(u[tt].w, -(1.0f / NA), T4.w);
            nt_store4(&out4[t * 48 + 32 + cg], o);
        }
    };

    // rolling pipeline over 4 rows: loads of row k+2 overlap stores of row k
    float4 A[8], B[8];
    load_row(A, 0);
    load_row(B, 1);
    do_row(A, 0);
    load_row(A, 2);
    do_row(B, 1);
    load_row(B, 3);
    do_row(A, 2);
    do_row(B, 3);
}

extern "C" void kernel_launch(void* const* d_in, const int* in_sizes, int n_in,
                              void* d_out, int out_size, void* d_ws, size_t ws_size,
                              hipStream_t stream) {
    const float* h        = (const float*)d_in[0];
    const float* policies = (const float*)d_in[1];
    const float* actions  = (const float*)d_in[2];
    const float* obs_proc = (const float*)d_in[3];
    const float* noise    = (const float*)d_in[4];
    const float* Wk       = (const float*)d_in[5];
    const float* bk       = (const float*)d_in[6];
    const float* Wq       = (const float*)d_in[7];
    const float* bq       = (const float*)d_in[8];

    float* out = (float*)d_out;
    float* obs_final = out;                                      // [8192,32,192]
    float* w_out = out + (size_t)NB * NA * NA * (NIN + NACT);    // [8192,32,1]

    k1_qk_obscopy<<<NB + NB * NA, 256, 0, stream>>>(h, Wk, bk, Wq, bq, obs_proc,
                                                    obs_final, w_out);
    k2_zmix<<<512, 256, 0, stream>>>(policies, actions, noise, w_out, obs_final);
}